// Round 1
// baseline (1028.248 us; speedup 1.0000x reference)
//
#include <hip/hip_runtime.h>
#include <math.h>

// Problem constants (from reference): N=32, HW=4096, C=1024, M=0.5*C, P=0.9
constexpr int Nn  = 32;
constexpr int HWn = 4096;
constexpr int Cn  = 1024;
constexpr int Mn  = 512;

// ---------------------------------------------------------------------------
// Kernel 1: per-(n,c) spatial sum of x over HW, accumulated in double.
// Grid: (N, 32) — each block handles one n and a 128-row HW chunk, all C.
// Thread t covers channels 4t..4t+3 via float4 loads (fully coalesced:
// wave of 64 threads reads 1 KiB contiguous per row).
// Partial sums land in ws via double atomicAdd (global_atomic_add_f64);
// double accumulation makes the result order-independent to ~1e-15 rel,
// which is what keeps the top-M selection bit-stable vs the f64 np reference.
// ---------------------------------------------------------------------------
__global__ __launch_bounds__(256) void score_kernel(const float* __restrict__ x,
                                                    double* __restrict__ score_sum) {
  const int n     = blockIdx.x;
  const int chunk = blockIdx.y;   // 0..31, 128 HW rows each
  const int t     = threadIdx.x;  // 0..255

  const float4* xp = (const float4*)(x + (size_t)n * HWn * Cn)
                     + (size_t)chunk * 128 * (Cn / 4) + t;
  double s0 = 0.0, s1 = 0.0, s2 = 0.0, s3 = 0.0;
#pragma unroll 4
  for (int i = 0; i < 128; ++i) {
    float4 v = xp[(size_t)i * (Cn / 4)];
    s0 += (double)v.x; s1 += (double)v.y; s2 += (double)v.z; s3 += (double)v.w;
  }
  double* dst = score_sum + (size_t)n * Cn + 4 * t;
  atomicAdd(dst + 0, s0);
  atomicAdd(dst + 1, s1);
  atomicAdd(dst + 2, s2);
  atomicAdd(dst + 3, s3);
}

// ---------------------------------------------------------------------------
// Kernel 2: per-row selection + alpha + mask build. One block per n.
// key[c] = r^(1/score) in double; sel[c] = (count of keys strictly > key[c]) < M
// (tie-equivalent to key >= M-th-largest). alpha = sum(score)/sum(sel*score).
// maskf[n,c] = (sel && u < 0.9) ? alpha : 0.
// ---------------------------------------------------------------------------
__global__ __launch_bounds__(256) void select_kernel(const float* __restrict__ r,
                                                     const float* __restrict__ u,
                                                     const double* __restrict__ score_sum,
                                                     float* __restrict__ maskf) {
  const int n = blockIdx.x;
  const int t = threadIdx.x;  // 0..255, each owns channels 4t..4t+3

  __shared__ double keys[Cn];
  __shared__ double wtot[4], wsel[4], bcast[2];

  double sc[4], ky[4];
#pragma unroll
  for (int j = 0; j < 4; ++j) {
    const int c = 4 * t + j;
    const double s = score_sum[(size_t)n * Cn + c] * (1.0 / (double)HWn);
    sc[j] = s;
    const double rr = (double)r[(size_t)n * Cn + c];
    ky[j] = pow(rr, 1.0 / s);
    keys[c] = ky[j];
  }
  __syncthreads();

  double tot = 0.0, selsum = 0.0;
  bool sel[4];
#pragma unroll
  for (int j = 0; j < 4; ++j) {
    const double k = ky[j];
    int cnt = 0;
    for (int i = 0; i < Cn; ++i) cnt += (keys[i] > k) ? 1 : 0;  // LDS broadcast reads
    sel[j] = (cnt < Mn);
    tot += sc[j];
    if (sel[j]) selsum += sc[j];
  }

  // wave (64-lane) reduction, then cross-wave via LDS
  for (int off = 32; off > 0; off >>= 1) {
    tot    += __shfl_down(tot, off);
    selsum += __shfl_down(selsum, off);
  }
  const int wave = t >> 6, lane = t & 63;
  if (lane == 0) { wtot[wave] = tot; wsel[wave] = selsum; }
  __syncthreads();
  if (t == 0) {
    double a = 0.0, b = 0.0;
    for (int i = 0; i < 4; ++i) { a += wtot[i]; b += wsel[i]; }
    bcast[0] = a; bcast[1] = b;
  }
  __syncthreads();
  const double alpha = bcast[0] / bcast[1];

#pragma unroll
  for (int j = 0; j < 4; ++j) {
    const int c = 4 * t + j;
    const bool gate = sel[j] && ((double)u[(size_t)n * Cn + c] < 0.9);
    maskf[(size_t)n * Cn + c] = gate ? (float)alpha : 0.0f;
  }
}

// ---------------------------------------------------------------------------
// Kernel 3: out[n,hw,c] = x[n,hw,c] * maskf[n,c]. Pure streaming multiply,
// float4 grid-stride. maskf (128 KiB) stays cache-resident.
// All index math uses power-of-two masks/shifts: C/4=256=2^8, HW*C/4=2^20.
// ---------------------------------------------------------------------------
__global__ __launch_bounds__(256) void scale_kernel(const float* __restrict__ x,
                                                    const float* __restrict__ maskf,
                                                    float* __restrict__ out) {
  const size_t total4 = (size_t)Nn * HWn * Cn / 4;  // 2^25
  const size_t stride = (size_t)gridDim.x * blockDim.x;
  const float4* x4 = (const float4*)x;
  const float4* m4 = (const float4*)maskf;
  float4* o4 = (float4*)out;

  for (size_t i = (size_t)blockIdx.x * blockDim.x + threadIdx.x; i < total4; i += stride) {
    const int c4 = (int)(i & (Cn / 4 - 1));        // i % 256
    const int n  = (int)(i >> 20);                 // i / (HW*C/4)
    float4 v = x4[i];
    const float4 m = m4[(size_t)n * (Cn / 4) + c4];
    v.x *= m.x; v.y *= m.y; v.z *= m.z; v.w *= m.w;
    o4[i] = v;
  }
}

extern "C" void kernel_launch(void* const* d_in, const int* in_sizes, int n_in,
                              void* d_out, int out_size, void* d_ws, size_t ws_size,
                              hipStream_t stream) {
  const float* x = (const float*)d_in[0];  // (N, HW, C)
  const float* r = (const float*)d_in[1];  // (N, C)
  const float* u = (const float*)d_in[2];  // (N, C)
  float* out = (float*)d_out;

  // ws layout: [0, N*C*8) double score_sum | [N*C*8, +N*C*4) float maskf
  double* score_sum = (double*)d_ws;
  float*  maskf     = (float*)((char*)d_ws + (size_t)Nn * Cn * sizeof(double));

  // ws is re-poisoned to 0xAA before every timed call — zero the accumulator.
  hipMemsetAsync(d_ws, 0, (size_t)Nn * Cn * sizeof(double), stream);

  score_kernel<<<dim3(Nn, 32), 256, 0, stream>>>(x, score_sum);
  select_kernel<<<Nn, 256, 0, stream>>>(r, u, score_sum, maskf);
  scale_kernel<<<2048, 256, 0, stream>>>(x, maskf, out);
}